// Round 1
// baseline (586.074 us; speedup 1.0000x reference)
//
#include <hip/hip_runtime.h>
#include <cmath>
#include <cstdint>

#define NROWS 65536
#define DIMN  256
#define NRF   256
#define OUTD  1024
#define KDIM  1024   // 4*NRF
#define MCOEF 0.001f

typedef __bf16 v8bf __attribute__((ext_vector_type(8)));
typedef float  v4f  __attribute__((ext_vector_type(4)));

__device__ __forceinline__ unsigned short f2bf(float f) {
  unsigned int u = __float_as_uint(f);
  u += 0x7fffu + ((u >> 16) & 1u);   // round-to-nearest-even
  return (unsigned short)(u >> 16);
}

__device__ __forceinline__ void async_copy16(const void* g, void* l) {
  __builtin_amdgcn_global_load_lds(
      (const __attribute__((address_space(1))) void*)g,
      (__attribute__((address_space(3))) void*)l, 16, 0, 0);
}

// rows x 256 fp32 -> scaled bf16 + fp32 row sum-of-squares (of scaled values)
__global__ __launch_bounds__(256) void prep_rows(
    const float* __restrict__ src, unsigned short* __restrict__ dst,
    float* __restrict__ sqout, float scl, int rows) {
  int row  = blockIdx.x * 4 + (threadIdx.x >> 6);
  int lane = threadIdx.x & 63;
  if (row >= rows) return;
  float4 v = ((const float4*)(src + (size_t)row * DIMN))[lane];
  v.x *= scl; v.y *= scl; v.z *= scl; v.w *= scl;
  float ss = v.x * v.x + v.y * v.y + v.z * v.z + v.w * v.w;
  ushort4 o;
  o.x = f2bf(v.x); o.y = f2bf(v.y); o.z = f2bf(v.z); o.w = f2bf(v.w);
  ((ushort4*)(dst + (size_t)row * DIMN))[lane] = o;
#pragma unroll
  for (int off = 32; off > 0; off >>= 1) ss += __shfl_down(ss, off, 64);
  if (lane == 0) sqout[row] = ss;
}

// proj -> bf16, and mg2[i] = M * ||proj_i||^2 (fp32)
__global__ __launch_bounds__(64) void prep_rf(
    const float* __restrict__ proj, unsigned short* __restrict__ projbf,
    float* __restrict__ mg2) {
  int i = blockIdx.x;
  int lane = threadIdx.x;  // 64 threads
  float4 v = ((const float4*)(proj + (size_t)i * DIMN))[lane];
  ushort4 o;
  o.x = f2bf(v.x); o.y = f2bf(v.y); o.z = f2bf(v.z); o.w = f2bf(v.w);
  ((ushort4*)(projbf + (size_t)i * DIMN))[lane] = o;
  float ss = v.x * v.x + v.y * v.y + v.z * v.z + v.w * v.w;
#pragma unroll
  for (int off = 32; off > 0; off >>= 1) ss += __shfl_down(ss, off, 64);
  if (lane == 0) mg2[i] = MCOEF * ss;
}

// Fused: px = A @ proj^T via MFMA (64 rows x 256 rfs per block), then the
// exp/sincos feature epilogue, writing rows x 1024 bf16:
//   [0..255]=sR*e+cos, [256..511]=sR*e-cos, [512..767]=sI*e+sin, [768..1023]=-sI*e-sin
__global__ __launch_bounds__(256) void fused_features(
    const unsigned short* __restrict__ Am,   // rows x 256 bf16 (already scaled)
    const float* __restrict__ sq,            // rows, fp32 ||v||^2
    const float* __restrict__ bias,          // may be null; raw b, scaled by bscl
    float bscl,
    const float* __restrict__ xr_g, const float* __restrict__ xi_g,
    const float* __restrict__ mg2_g,
    const unsigned short* __restrict__ projbf,  // 256 x 256 bf16
    unsigned short* __restrict__ Fout,       // rows x 1024 bf16
    float sR, float sI, float scaleC) {
  __shared__ __align__(16) unsigned short As[64 * 32];
  __shared__ __align__(16) unsigned short Bs[256 * 32];
  __shared__ float xr_s[256], xi_s[256], c1_s[256], c2_s[256], mg2_s[256];
  __shared__ float sq_s[64], bias_s[64];

  int t = threadIdx.x;
  int lane = t & 63;
  int w = t >> 6;
  int blockRow = blockIdx.x * 64;

  {
    float a = xr_g[t], b = xi_g[t];
    xr_s[t] = a; xi_s[t] = b;
    c1_s[t] = a * a - b * b;   // Re(z^2)
    c2_s[t] = 2.f * a * b;     // Im(z^2)
    mg2_s[t] = mg2_g[t];
  }
  if (t < 64) {
    int r = blockRow + t;
    sq_s[t] = sq[r];
    bias_s[t] = bias ? bias[r] * bscl : 0.f;
  }

  v4f acc[4][4];
#pragma unroll
  for (int a = 0; a < 4; a++)
#pragma unroll
    for (int b = 0; b < 4; b++)
#pragma unroll
      for (int q = 0; q < 4; q++) acc[a][b][q] = 0.f;

  for (int kb = 0; kb < DIMN; kb += 32) {
    {
      int idx = t;                       // 64x32 bf16 tile = 4 KB = 256 lanes*16B
      int row = idx >> 2, kc = (idx & 3) * 8;
      async_copy16(Am + (size_t)(blockRow + row) * DIMN + kb + kc,
                   As + (idx & ~63) * 8);
    }
#pragma unroll
    for (int r = 0; r < 4; r++) {        // 256x32 tile = 16 KB
      int idx = r * 256 + t;
      int row = idx >> 2, kc = (idx & 3) * 8;
      async_copy16(projbf + (size_t)row * DIMN + kb + kc,
                   Bs + (idx & ~63) * 8);
    }
    __syncthreads();
    v8bf af[4], bfv[4];
#pragma unroll
    for (int mi = 0; mi < 4; mi++)
      af[mi] = *(const v8bf*)&As[(mi * 16 + (lane & 15)) * 32 + (lane >> 4) * 8];
#pragma unroll
    for (int ni = 0; ni < 4; ni++)
      bfv[ni] = *(const v8bf*)&Bs[(w * 64 + ni * 16 + (lane & 15)) * 32 + (lane >> 4) * 8];
#pragma unroll
    for (int mi = 0; mi < 4; mi++)
#pragma unroll
      for (int ni = 0; ni < 4; ni++)
        acc[mi][ni] = __builtin_amdgcn_mfma_f32_16x16x32_bf16(
            af[mi], bfv[ni], acc[mi][ni], 0, 0, 0);
    __syncthreads();
  }

#pragma unroll
  for (int mi = 0; mi < 4; mi++) {
#pragma unroll
    for (int ni = 0; ni < 4; ni++) {
#pragma unroll
      for (int reg = 0; reg < 4; reg++) {
        int rloc = mi * 16 + (lane >> 4) * 4 + reg;          // D row = x row
        int i    = w * 64 + ni * 16 + (lane & 15);           // D col = rf index
        float px = acc[mi][ni][reg];
        float tt = scaleC * px + bias_s[rloc];
        float u  = 0.5f * sq_s[rloc];
        float aa = u * c1_s[i] + mg2_s[i];
        float bb = u * c2_s[i];
        float txr = tt * xr_s[i];
        float txi = tt * xi_s[i];
        float erp = __expf(txr - aa);
        float erm = __expf(-txr - aa);
        float s1, cc1, s2, cc2;
        __sincosf(txi - bb, &s1, &cc1);
        __sincosf(txi + bb, &s2, &cc2);
        unsigned short* o = Fout + (size_t)(blockRow + rloc) * KDIM;
        o[i]             = f2bf(sR * erp * cc1);
        o[NRF + i]       = f2bf(sR * erm * cc2);
        o[2 * NRF + i]   = f2bf(sI * erp * s1);
        o[3 * NRF + i]   = f2bf(-sI * erm * s2);
      }
    }
  }
}

// out[n,o] = sum_k A[n,k]*B[o,k]; 128x128 tile, BK=32, m97 structure
__global__ __launch_bounds__(256) void gemm_bt(
    const unsigned short* __restrict__ A,   // NROWS x KDIM bf16
    const unsigned short* __restrict__ B,   // OUTD x KDIM bf16
    float* __restrict__ C) {                // NROWS x OUTD fp32
  __shared__ __align__(16) unsigned short As[128 * 32];
  __shared__ __align__(16) unsigned short Bs[128 * 32];
  int t = threadIdx.x;
  int lane = t & 63;
  int w = t >> 6;
  int wm = w >> 1, wn = w & 1;
  size_t bm = (size_t)blockIdx.y * 128;   // rows of x-features
  size_t bn = (size_t)blockIdx.x * 128;   // output columns

  v4f acc[4][4];
#pragma unroll
  for (int a = 0; a < 4; a++)
#pragma unroll
    for (int b = 0; b < 4; b++)
#pragma unroll
      for (int q = 0; q < 4; q++) acc[a][b][q] = 0.f;

  for (int kb = 0; kb < KDIM; kb += 32) {
#pragma unroll
    for (int r = 0; r < 2; r++) {
      int idx = r * 256 + t;
      int row = idx >> 2, kc = (idx & 3) * 8;
      async_copy16(A + (bm + row) * KDIM + kb + kc, As + (idx & ~63) * 8);
      async_copy16(B + (bn + row) * KDIM + kb + kc, Bs + (idx & ~63) * 8);
    }
    __syncthreads();
    v8bf af[4], bfv[4];
#pragma unroll
    for (int mi = 0; mi < 4; mi++)
      af[mi] = *(const v8bf*)&As[(wm * 64 + mi * 16 + (lane & 15)) * 32 + (lane >> 4) * 8];
#pragma unroll
    for (int ni = 0; ni < 4; ni++)
      bfv[ni] = *(const v8bf*)&Bs[(wn * 64 + ni * 16 + (lane & 15)) * 32 + (lane >> 4) * 8];
#pragma unroll
    for (int mi = 0; mi < 4; mi++)
#pragma unroll
      for (int ni = 0; ni < 4; ni++)
        acc[mi][ni] = __builtin_amdgcn_mfma_f32_16x16x32_bf16(
            af[mi], bfv[ni], acc[mi][ni], 0, 0, 0);
    __syncthreads();
  }

#pragma unroll
  for (int mi = 0; mi < 4; mi++)
#pragma unroll
    for (int ni = 0; ni < 4; ni++)
#pragma unroll
      for (int reg = 0; reg < 4; reg++) {
        size_t row = bm + wm * 64 + mi * 16 + (lane >> 4) * 4 + reg;
        size_t col = bn + wn * 64 + ni * 16 + (lane & 15);
        C[row * OUTD + col] = acc[mi][ni][reg];
      }
}

extern "C" void kernel_launch(void* const* d_in, const int* in_sizes, int n_in,
                              void* d_out, int out_size, void* d_ws, size_t ws_size,
                              hipStream_t stream) {
  (void)in_sizes; (void)n_in; (void)out_size;
  const float* x    = (const float*)d_in[0];
  const float* iw   = (const float*)d_in[1];
  const float* bvec = (const float*)d_in[2];
  const float* proj = (const float*)d_in[3];
  const float* xr   = (const float*)d_in[4];
  const float* xi   = (const float*)d_in[5];
  float* out = (float*)d_out;

  char* ws = (char*)d_ws;
  size_t off = 0;
  auto take = [&](size_t bytes) {
    char* p = ws + off;
    off = (off + bytes + 255) & ~(size_t)255;
    return p;
  };
  unsigned short* F      = (unsigned short*)take((size_t)NROWS * KDIM * 2);  // 134 MB
  unsigned short* xs     = (unsigned short*)take((size_t)NROWS * DIMN * 2);  // 33.5 MB
  unsigned short* Wp     = (unsigned short*)take((size_t)OUTD * KDIM * 2);   // 2 MB
  unsigned short* wmb    = (unsigned short*)take((size_t)OUTD * DIMN * 2);   // 0.5 MB
  unsigned short* projbf = (unsigned short*)take((size_t)NRF * DIMN * 2);    // 128 KB
  float* sqx = (float*)take((size_t)NROWS * 4);
  float* sqw = (float*)take((size_t)OUTD * 4);
  float* mg2 = (float*)take((size_t)NRF * 4);
  if (ws_size < off) return;  // workspace too small: bail cleanly (diagnosable)

  const float  scaleC = sqrtf(1.f + 4.f * MCOEF);                 // sqrt(1.004)
  const double c2d    = 0.5 * exp(128.0 * log(1.0 + 4.0 * 0.001));// c^2
  const float  invSR  = 0.0625f;                                   // 1/sqrt(256)
  const float  sRw    = (float)(c2d * 0.0625);

  prep_rows<<<NROWS / 4, 256, 0, stream>>>(x, xs, sqx, 1.f / DIMN, NROWS);
  prep_rows<<<OUTD / 4, 256, 0, stream>>>(iw, wmb, sqw, 0.25f, OUTD);
  prep_rf<<<NRF, 64, 0, stream>>>(proj, projbf, mg2);
  fused_features<<<NROWS / 64, 256, 0, stream>>>(
      xs, sqx, nullptr, 0.f, xr, xi, mg2, projbf, F, invSR, invSR, scaleC);
  fused_features<<<OUTD / 64, 256, 0, stream>>>(
      wmb, sqw, bvec, 0.25f, xr, xi, mg2, projbf, Wp, sRw, -sRw, scaleC);
  gemm_bt<<<dim3(8, 512), 256, 0, stream>>>(F, Wp, out);
}

// Round 2
// 570.159 us; speedup vs baseline: 1.0279x; 1.0279x over previous
//
#include <hip/hip_runtime.h>
#include <cmath>
#include <cstdint>

#define NROWS 65536
#define DIMN  256
#define NRF   256
#define OUTD  1024
#define KDIM  1024   // 4*NRF
#define MCOEF 0.001f

typedef __bf16 v8bf __attribute__((ext_vector_type(8)));
typedef float  v4f  __attribute__((ext_vector_type(4)));
typedef unsigned short us8 __attribute__((ext_vector_type(8)));

__device__ __forceinline__ unsigned short f2bf(float f) {
  unsigned int u = __float_as_uint(f);
  u += 0x7fffu + ((u >> 16) & 1u);   // round-to-nearest-even
  return (unsigned short)(u >> 16);
}

__device__ __forceinline__ void async_copy16(const void* g, void* l) {
  __builtin_amdgcn_global_load_lds(
      (const __attribute__((address_space(1))) void*)g,
      (__attribute__((address_space(3))) void*)l, 16, 0, 0);
}

// proj -> bf16, and mg2[i] = M * ||proj_i||^2 (fp32)
__global__ __launch_bounds__(64) void prep_rf(
    const float* __restrict__ proj, unsigned short* __restrict__ projbf,
    float* __restrict__ mg2) {
  int i = blockIdx.x;
  int lane = threadIdx.x;  // 64 threads
  float4 v = ((const float4*)(proj + (size_t)i * DIMN))[lane];
  ushort4 o;
  o.x = f2bf(v.x); o.y = f2bf(v.y); o.z = f2bf(v.z); o.w = f2bf(v.w);
  ((ushort4*)(projbf + (size_t)i * DIMN))[lane] = o;
  float ss = v.x * v.x + v.y * v.y + v.z * v.z + v.w * v.w;
#pragma unroll
  for (int off = 32; off > 0; off >>= 1) ss += __shfl_down(ss, off, 64);
  if (lane == 0) mg2[i] = MCOEF * ss;
}

// Fused: fp32 source rows -> scale -> bf16 A-tile (in LDS) + row ||.||^2,
// px = A @ proj^T via MFMA (64 rows x 256 rfs per block), exp/sincos feature
// epilogue staged through LDS, coalesced ushort8 stores.
// Output layout per row (KDIM=1024 bf16):
//   [0..255]=sR*e+cos, [256..511]=sR*e-cos, [512..767]=sI*e+sin, [768..1023]=-sI*e-sin
__global__ __launch_bounds__(256) void fused_features(
    const float* __restrict__ src,           // rows x 256 fp32 (unscaled)
    float scl,                               // row scale (1/256 or 1/4)
    const float* __restrict__ bias,          // may be null; raw b, scaled by bscl
    float bscl,
    const float* __restrict__ xr_g, const float* __restrict__ xi_g,
    const float* __restrict__ mg2_g,
    const unsigned short* __restrict__ projbf,  // 256 x 256 bf16
    unsigned short* __restrict__ Fout,       // rows x 1024 bf16
    float sR, float sI, float scaleC) {
  // 32 KB union: K-loop uses As(4K)+Bs(16K); epilogue reuses all as Os(32K)
  __shared__ __align__(16) unsigned short big[16 * 1024];
  unsigned short* As = big;          // 64 rows x 32 k, row-major
  unsigned short* Bs = big + 2048;   // 256 rows x 32 k
  unsigned short* Os = big;          // 16 rows x 1024 cols
  __shared__ float xr_s[256], xi_s[256], c1_s[256], c2_s[256], mg2_s[256];
  __shared__ float sq_s[64], bias_s[64];

  int t = threadIdx.x;
  int lane = t & 63;
  int w = t >> 6;
  int blockRow = blockIdx.x * 64;

  {
    float a = xr_g[t], b = xi_g[t];
    xr_s[t] = a; xi_s[t] = b;
    c1_s[t] = a * a - b * b;   // Re(z^2)
    c2_s[t] = 2.f * a * b;     // Im(z^2)
    mg2_s[t] = mg2_g[t];
  }
  if (t < 64) bias_s[t] = bias ? bias[blockRow + t] * bscl : 0.f;

  v4f acc[4][4];
#pragma unroll
  for (int a = 0; a < 4; a++)
#pragma unroll
    for (int b = 0; b < 4; b++)
#pragma unroll
      for (int q = 0; q < 4; q++) acc[a][b][q] = 0.f;

  // each thread owns 8 k-columns of one A row: row = t>>2, cols sub*8..sub*8+7
  int arow = t >> 2, sub = t & 3;
  const float* srow = src + (size_t)(blockRow + arow) * DIMN + sub * 8;
  float ss = 0.f;

  for (int kb = 0; kb < DIMN; kb += 32) {
    // A: fp32 load -> scale -> bf16 -> LDS (+ running sum of squares)
    float4 v0 = *(const float4*)(srow + kb);
    float4 v1 = *(const float4*)(srow + kb + 4);
    v0.x *= scl; v0.y *= scl; v0.z *= scl; v0.w *= scl;
    v1.x *= scl; v1.y *= scl; v1.z *= scl; v1.w *= scl;
    ss += v0.x * v0.x + v0.y * v0.y + v0.z * v0.z + v0.w * v0.w +
          v1.x * v1.x + v1.y * v1.y + v1.z * v1.z + v1.w * v1.w;
    us8 o;
    o[0] = f2bf(v0.x); o[1] = f2bf(v0.y); o[2] = f2bf(v0.z); o[3] = f2bf(v0.w);
    o[4] = f2bf(v1.x); o[5] = f2bf(v1.y); o[6] = f2bf(v1.z); o[7] = f2bf(v1.w);
    *(us8*)&As[arow * 32 + sub * 8] = o;
    // B: 256x32 tile = 16 KB via global_load_lds
#pragma unroll
    for (int r = 0; r < 4; r++) {
      int idx = r * 256 + t;
      int row = idx >> 2, kc = (idx & 3) * 8;
      async_copy16(projbf + (size_t)row * DIMN + kb + kc,
                   Bs + (idx & ~63) * 8);
    }
    __syncthreads();
    v8bf af[4], bfv[4];
#pragma unroll
    for (int mi = 0; mi < 4; mi++)
      af[mi] = *(const v8bf*)&As[(mi * 16 + (lane & 15)) * 32 + (lane >> 4) * 8];
#pragma unroll
    for (int ni = 0; ni < 4; ni++)
      bfv[ni] = *(const v8bf*)&Bs[(w * 64 + ni * 16 + (lane & 15)) * 32 + (lane >> 4) * 8];
#pragma unroll
    for (int mi = 0; mi < 4; mi++)
#pragma unroll
      for (int ni = 0; ni < 4; ni++)
        acc[mi][ni] = __builtin_amdgcn_mfma_f32_16x16x32_bf16(
            af[mi], bfv[ni], acc[mi][ni], 0, 0, 0);
    __syncthreads();
  }

  // row sum-of-squares: reduce the 4 sub-threads of each row
  ss += __shfl_xor(ss, 1, 64);
  ss += __shfl_xor(ss, 2, 64);
  if (sub == 0) sq_s[arow] = ss;

#pragma unroll
  for (int mi = 0; mi < 4; mi++) {
    __syncthreads();   // Os (=As/Bs space) free to overwrite; sq_s visible
#pragma unroll
    for (int ni = 0; ni < 4; ni++) {
#pragma unroll
      for (int reg = 0; reg < 4; reg++) {
        int rl    = (lane >> 4) * 4 + reg;       // row within 16-row mi-tile
        int rglob = mi * 16 + rl;                // row within block
        int i     = w * 64 + ni * 16 + (lane & 15);  // rf index
        float px = acc[mi][ni][reg];
        float tt = scaleC * px + bias_s[rglob];
        float u  = 0.5f * sq_s[rglob];
        float aa = u * c1_s[i] + mg2_s[i];
        float bb = u * c2_s[i];
        float txr = tt * xr_s[i];
        float txi = tt * xi_s[i];
        float erp = __expf(txr - aa);
        float erm = __expf(-txr - aa);
        float s1, cc1, s2, cc2;
        __sincosf(txi - bb, &s1, &cc1);
        __sincosf(txi + bb, &s2, &cc2);
        Os[rl * KDIM + i]            = f2bf(sR * erp * cc1);
        Os[rl * KDIM + NRF + i]      = f2bf(sR * erm * cc2);
        Os[rl * KDIM + 2 * NRF + i]  = f2bf(sI * erp * s1);
        Os[rl * KDIM + 3 * NRF + i]  = f2bf(-sI * erm * s2);
      }
    }
    __syncthreads();
    // stream 16 rows x 1024 cols bf16 = 32 KB, 16 B per lane, coalesced
#pragma unroll
    for (int j = 0; j < 8; j++) {
      int chunk = j * 256 + t;          // 2048 chunks of 8 shorts
      int rowo  = chunk >> 7;           // 0..15
      int off   = (chunk & 127) * 8;    // 0..1016
      *(us8*)(Fout + (size_t)(blockRow + mi * 16 + rowo) * KDIM + off) =
          *(const us8*)&Os[rowo * KDIM + off];
    }
  }
}

// out[n,o] = sum_k A[n,k]*B[o,k]; 128x128 tile, BK=32, m97 structure.
// XCD-aware swizzle: lid&7 = XCD; each XCD owns 64 contiguous row panels and
// sweeps the 8 col tiles of one panel consecutively -> F panel hot in that
// XCD's L2 across its 8 reuses; Wp (2 MB) always L2-resident.
__global__ __launch_bounds__(256) void gemm_bt(
    const unsigned short* __restrict__ A,   // NROWS x KDIM bf16
    const unsigned short* __restrict__ B,   // OUTD x KDIM bf16
    float* __restrict__ C) {                // NROWS x OUTD fp32
  __shared__ __align__(16) unsigned short As[128 * 32];
  __shared__ __align__(16) unsigned short Bs[128 * 32];
  int t = threadIdx.x;
  int lane = t & 63;
  int w = t >> 6;
  int wm = w >> 1, wn = w & 1;
  int lid = blockIdx.x;
  int slot = lid >> 3;                      // 0..511
  size_t bm = (size_t)(((lid & 7) * 64) + (slot >> 3)) * 128;  // row panel
  size_t bn = (size_t)(slot & 7) * 128;                        // col panel

  v4f acc[4][4];
#pragma unroll
  for (int a = 0; a < 4; a++)
#pragma unroll
    for (int b = 0; b < 4; b++)
#pragma unroll
      for (int q = 0; q < 4; q++) acc[a][b][q] = 0.f;

  for (int kb = 0; kb < KDIM; kb += 32) {
#pragma unroll
    for (int r = 0; r < 2; r++) {
      int idx = r * 256 + t;
      int row = idx >> 2, kc = (idx & 3) * 8;
      async_copy16(A + (bm + row) * KDIM + kb + kc, As + (idx & ~63) * 8);
      async_copy16(B + (bn + row) * KDIM + kb + kc, Bs + (idx & ~63) * 8);
    }
    __syncthreads();
    v8bf af[4], bfv[4];
#pragma unroll
    for (int mi = 0; mi < 4; mi++)
      af[mi] = *(const v8bf*)&As[(wm * 64 + mi * 16 + (lane & 15)) * 32 + (lane >> 4) * 8];
#pragma unroll
    for (int ni = 0; ni < 4; ni++)
      bfv[ni] = *(const v8bf*)&Bs[(wn * 64 + ni * 16 + (lane & 15)) * 32 + (lane >> 4) * 8];
#pragma unroll
    for (int mi = 0; mi < 4; mi++)
#pragma unroll
      for (int ni = 0; ni < 4; ni++)
        acc[mi][ni] = __builtin_amdgcn_mfma_f32_16x16x32_bf16(
            af[mi], bfv[ni], acc[mi][ni], 0, 0, 0);
    __syncthreads();
  }

#pragma unroll
  for (int mi = 0; mi < 4; mi++)
#pragma unroll
    for (int ni = 0; ni < 4; ni++)
#pragma unroll
      for (int reg = 0; reg < 4; reg++) {
        size_t row = bm + wm * 64 + mi * 16 + (lane >> 4) * 4 + reg;
        size_t col = bn + wn * 64 + ni * 16 + (lane & 15);
        C[row * OUTD + col] = acc[mi][ni][reg];
      }
}

extern "C" void kernel_launch(void* const* d_in, const int* in_sizes, int n_in,
                              void* d_out, int out_size, void* d_ws, size_t ws_size,
                              hipStream_t stream) {
  (void)in_sizes; (void)n_in; (void)out_size;
  const float* x    = (const float*)d_in[0];
  const float* iw   = (const float*)d_in[1];
  const float* bvec = (const float*)d_in[2];
  const float* proj = (const float*)d_in[3];
  const float* xr   = (const float*)d_in[4];
  const float* xi   = (const float*)d_in[5];
  float* out = (float*)d_out;

  char* ws = (char*)d_ws;
  size_t off = 0;
  auto take = [&](size_t bytes) {
    char* p = ws + off;
    off = (off + bytes + 255) & ~(size_t)255;
    return p;
  };
  unsigned short* F      = (unsigned short*)take((size_t)NROWS * KDIM * 2);  // 134 MB
  unsigned short* Wp     = (unsigned short*)take((size_t)OUTD * KDIM * 2);   // 2 MB
  unsigned short* projbf = (unsigned short*)take((size_t)NRF * DIMN * 2);    // 128 KB
  float* mg2 = (float*)take((size_t)NRF * 4);
  if (ws_size < off) return;  // workspace too small: bail cleanly (diagnosable)

  const float  scaleC = sqrtf(1.f + 4.f * MCOEF);                 // sqrt(1.004)
  const double c2d    = 0.5 * exp(128.0 * log(1.0 + 4.0 * 0.001));// c^2
  const float  invSR  = 0.0625f;                                   // 1/sqrt(256)
  const float  sRw    = (float)(c2d * 0.0625);

  prep_rf<<<NRF, 64, 0, stream>>>(proj, projbf, mg2);
  fused_features<<<NROWS / 64, 256, 0, stream>>>(
      x, 1.f / DIMN, nullptr, 0.f, xr, xi, mg2, projbf, F, invSR, invSR, scaleC);
  fused_features<<<OUTD / 64, 256, 0, stream>>>(
      iw, 0.25f, bvec, 0.25f, xr, xi, mg2, projbf, Wp, sRw, -sRw, scaleC);
  gemm_bt<<<4096, 256, 0, stream>>>(F, Wp, out);
}

// Round 3
// 568.494 us; speedup vs baseline: 1.0309x; 1.0029x over previous
//
#include <hip/hip_runtime.h>
#include <cmath>
#include <cstdint>

#define NROWS 65536
#define DIMN  256
#define NRF   256
#define OUTD  1024
#define KDIM  1024   // 4*NRF
#define MCOEF 0.001f

typedef __bf16 v8bf __attribute__((ext_vector_type(8)));
typedef float  v4f  __attribute__((ext_vector_type(4)));
typedef unsigned short us8 __attribute__((ext_vector_type(8)));

__device__ __forceinline__ unsigned short f2bf(float f) {
  unsigned int u = __float_as_uint(f);
  u += 0x7fffu + ((u >> 16) & 1u);   // round-to-nearest-even
  return (unsigned short)(u >> 16);
}

__device__ __forceinline__ void async_copy16(const void* g, void* l) {
  __builtin_amdgcn_global_load_lds(
      (const __attribute__((address_space(1))) void*)g,
      (__attribute__((address_space(3))) void*)l, 16, 0, 0);
}

// XOR-swizzled tile layout (breaks the 8-way bank conflict of row-stride-64B):
//   LDS slot idx (16B granules) holds global 8-elem chunk ((idx&3)^((idx>>3)&3))
//   of row (idx>>2). Reader: row r, chunk c -> slot 4r + ((c ^ (r>>1)) & 3).
//   Over 16 consecutive rows, slot mod 8 covers each residue exactly twice
//   -> 2-way access = conflict-free (m136).
__device__ __forceinline__ int sw_slot(int r, int c) {
  return r * 4 + ((c ^ (r >> 1)) & 3);
}

// proj -> bf16, and mg2[i] = M * ||proj_i||^2 (fp32)
__global__ __launch_bounds__(64) void prep_rf(
    const float* __restrict__ proj, unsigned short* __restrict__ projbf,
    float* __restrict__ mg2) {
  int i = blockIdx.x;
  int lane = threadIdx.x;  // 64 threads
  float4 v = ((const float4*)(proj + (size_t)i * DIMN))[lane];
  ushort4 o;
  o.x = f2bf(v.x); o.y = f2bf(v.y); o.z = f2bf(v.z); o.w = f2bf(v.w);
  ((ushort4*)(projbf + (size_t)i * DIMN))[lane] = o;
  float ss = v.x * v.x + v.y * v.y + v.z * v.z + v.w * v.w;
#pragma unroll
  for (int off = 32; off > 0; off >>= 1) ss += __shfl_down(ss, off, 64);
  if (lane == 0) mg2[i] = MCOEF * ss;
}

// Fused: fp32 source rows -> scale -> bf16 A-tile (in LDS) + row ||.||^2,
// px = A @ proj^T via MFMA (64 rows x 256 rfs per block), exp/sincos feature
// epilogue staged through LDS, coalesced ushort8 stores.
__global__ __launch_bounds__(256) void fused_features(
    const float* __restrict__ src,           // rows x 256 fp32 (unscaled)
    float scl,                               // row scale (1/256 or 1/4)
    const float* __restrict__ bias,          // may be null; raw b, scaled by bscl
    float bscl,
    const float* __restrict__ xr_g, const float* __restrict__ xi_g,
    const float* __restrict__ mg2_g,
    const unsigned short* __restrict__ projbf,  // 256 x 256 bf16
    unsigned short* __restrict__ Fout,       // rows x 1024 bf16
    float sR, float sI, float scaleC) {
  // 32 KB union: K-loop uses As(4K)+Bs(16K); epilogue reuses all as Os(32K)
  __shared__ __align__(16) unsigned short big[16 * 1024];
  unsigned short* As = big;          // 64 rows x 32 k (swizzled slots)
  unsigned short* Bs = big + 2048;   // 256 rows x 32 k (swizzled slots)
  unsigned short* Os = big;          // 16 rows x 1024 cols
  __shared__ float xr_s[256], xi_s[256], c1_s[256], c2_s[256], mg2_s[256];
  __shared__ float sq_s[64], bias_s[64];

  int t = threadIdx.x;
  int lane = t & 63;
  int w = t >> 6;
  int blockRow = blockIdx.x * 64;

  {
    float a = xr_g[t], b = xi_g[t];
    xr_s[t] = a; xi_s[t] = b;
    c1_s[t] = a * a - b * b;   // Re(z^2)
    c2_s[t] = 2.f * a * b;     // Im(z^2)
    mg2_s[t] = mg2_g[t];
  }
  if (t < 64) bias_s[t] = bias ? bias[blockRow + t] * bscl : 0.f;

  v4f acc[4][4];
#pragma unroll
  for (int a = 0; a < 4; a++)
#pragma unroll
    for (int b = 0; b < 4; b++)
#pragma unroll
      for (int q = 0; q < 4; q++) acc[a][b][q] = 0.f;

  // each thread owns 8 k-columns of one A row: row = t>>2, chunk sub
  int arow = t >> 2, sub = t & 3;
  const float* srow = src + (size_t)(blockRow + arow) * DIMN + sub * 8;
  float ss = 0.f;

  for (int kb = 0; kb < DIMN; kb += 32) {
    // A: fp32 load -> scale -> bf16 -> LDS swizzled slot (+ sum of squares)
    float4 v0 = *(const float4*)(srow + kb);
    float4 v1 = *(const float4*)(srow + kb + 4);
    v0.x *= scl; v0.y *= scl; v0.z *= scl; v0.w *= scl;
    v1.x *= scl; v1.y *= scl; v1.z *= scl; v1.w *= scl;
    ss += v0.x * v0.x + v0.y * v0.y + v0.z * v0.z + v0.w * v0.w +
          v1.x * v1.x + v1.y * v1.y + v1.z * v1.z + v1.w * v1.w;
    us8 o;
    o[0] = f2bf(v0.x); o[1] = f2bf(v0.y); o[2] = f2bf(v0.z); o[3] = f2bf(v0.w);
    o[4] = f2bf(v1.x); o[5] = f2bf(v1.y); o[6] = f2bf(v1.z); o[7] = f2bf(v1.w);
    *(us8*)&As[sw_slot(arow, sub) * 8] = o;
    // B: 256x32 tile = 16 KB via global_load_lds, source-chunk swizzled
#pragma unroll
    for (int r = 0; r < 4; r++) {
      int idx = r * 256 + t;
      int row = idx >> 2, kc = ((idx & 3) ^ ((idx >> 3) & 3)) * 8;
      async_copy16(projbf + (size_t)row * DIMN + kb + kc,
                   Bs + (idx & ~63) * 8);
    }
    __syncthreads();
    v8bf af[4], bfv[4];
    int c = lane >> 4;
#pragma unroll
    for (int mi = 0; mi < 4; mi++)
      af[mi] = *(const v8bf*)&As[sw_slot(mi * 16 + (lane & 15), c) * 8];
#pragma unroll
    for (int ni = 0; ni < 4; ni++)
      bfv[ni] = *(const v8bf*)&Bs[sw_slot(w * 64 + ni * 16 + (lane & 15), c) * 8];
#pragma unroll
    for (int mi = 0; mi < 4; mi++)
#pragma unroll
      for (int ni = 0; ni < 4; ni++)
        acc[mi][ni] = __builtin_amdgcn_mfma_f32_16x16x32_bf16(
            af[mi], bfv[ni], acc[mi][ni], 0, 0, 0);
    __syncthreads();
  }

  // row sum-of-squares: reduce the 4 sub-threads of each row
  ss += __shfl_xor(ss, 1, 64);
  ss += __shfl_xor(ss, 2, 64);
  if (sub == 0) sq_s[arow] = ss;

#pragma unroll
  for (int mi = 0; mi < 4; mi++) {
    __syncthreads();   // Os (=As/Bs space) free to overwrite; sq_s visible
#pragma unroll
    for (int ni = 0; ni < 4; ni++) {
#pragma unroll
      for (int reg = 0; reg < 4; reg++) {
        int rl    = (lane >> 4) * 4 + reg;       // row within 16-row mi-tile
        int rglob = mi * 16 + rl;                // row within block
        int i     = w * 64 + ni * 16 + (lane & 15);  // rf index
        float px = acc[mi][ni][reg];
        float tt = scaleC * px + bias_s[rglob];
        float u  = 0.5f * sq_s[rglob];
        float aa = u * c1_s[i] + mg2_s[i];
        float bb = u * c2_s[i];
        float txr = tt * xr_s[i];
        float txi = tt * xi_s[i];
        float erp = __expf(txr - aa);
        float erm = __expf(-txr - aa);
        float s1, cc1, s2, cc2;
        __sincosf(txi - bb, &s1, &cc1);
        __sincosf(txi + bb, &s2, &cc2);
        Os[rl * KDIM + i]            = f2bf(sR * erp * cc1);
        Os[rl * KDIM + NRF + i]      = f2bf(sR * erm * cc2);
        Os[rl * KDIM + 2 * NRF + i]  = f2bf(sI * erp * s1);
        Os[rl * KDIM + 3 * NRF + i]  = f2bf(-sI * erm * s2);
      }
    }
    __syncthreads();
    // stream 16 rows x 1024 cols bf16 = 32 KB, 16 B per lane, coalesced
#pragma unroll
    for (int j = 0; j < 8; j++) {
      int chunk = j * 256 + t;          // 2048 chunks of 8 shorts
      int rowo  = chunk >> 7;           // 0..15
      int off   = (chunk & 127) * 8;    // 0..1016
      *(us8*)(Fout + (size_t)(blockRow + mi * 16 + rowo) * KDIM + off) =
          *(const us8*)&Os[rowo * KDIM + off];
    }
  }
}

// out[n,o] = sum_k A[n,k]*B[o,k]; 128x128 tile, BK=32, swizzled LDS,
// XCD-aware block mapping (lid&7 = XCD owns contiguous row panels).
__global__ __launch_bounds__(256) void gemm_bt(
    const unsigned short* __restrict__ A,   // NROWS x KDIM bf16
    const unsigned short* __restrict__ B,   // OUTD x KDIM bf16
    float* __restrict__ C) {                // NROWS x OUTD fp32
  __shared__ __align__(16) unsigned short As[128 * 32];
  __shared__ __align__(16) unsigned short Bs[128 * 32];
  int t = threadIdx.x;
  int lane = t & 63;
  int w = t >> 6;
  int wm = w >> 1, wn = w & 1;
  int lid = blockIdx.x;
  int slot = lid >> 3;                      // 0..511
  size_t bm = (size_t)(((lid & 7) * 64) + (slot >> 3)) * 128;  // row panel
  size_t bn = (size_t)(slot & 7) * 128;                        // col panel

  v4f acc[4][4];
#pragma unroll
  for (int a = 0; a < 4; a++)
#pragma unroll
    for (int b = 0; b < 4; b++)
#pragma unroll
      for (int q = 0; q < 4; q++) acc[a][b][q] = 0.f;

  for (int kb = 0; kb < KDIM; kb += 32) {
#pragma unroll
    for (int r = 0; r < 2; r++) {
      int idx = r * 256 + t;
      int row = idx >> 2, kc = ((idx & 3) ^ ((idx >> 3) & 3)) * 8;
      async_copy16(A + (bm + row) * KDIM + kb + kc, As + (idx & ~63) * 8);
      async_copy16(B + (bn + row) * KDIM + kb + kc, Bs + (idx & ~63) * 8);
    }
    __syncthreads();
    v8bf af[4], bfv[4];
    int c = lane >> 4;
#pragma unroll
    for (int mi = 0; mi < 4; mi++)
      af[mi] = *(const v8bf*)&As[sw_slot(wm * 64 + mi * 16 + (lane & 15), c) * 8];
#pragma unroll
    for (int ni = 0; ni < 4; ni++)
      bfv[ni] = *(const v8bf*)&Bs[sw_slot(wn * 64 + ni * 16 + (lane & 15), c) * 8];
#pragma unroll
    for (int mi = 0; mi < 4; mi++)
#pragma unroll
      for (int ni = 0; ni < 4; ni++)
        acc[mi][ni] = __builtin_amdgcn_mfma_f32_16x16x32_bf16(
            af[mi], bfv[ni], acc[mi][ni], 0, 0, 0);
    __syncthreads();
  }

#pragma unroll
  for (int mi = 0; mi < 4; mi++)
#pragma unroll
    for (int ni = 0; ni < 4; ni++)
#pragma unroll
      for (int reg = 0; reg < 4; reg++) {
        size_t row = bm + wm * 64 + mi * 16 + (lane >> 4) * 4 + reg;
        size_t col = bn + wn * 64 + ni * 16 + (lane & 15);
        C[row * OUTD + col] = acc[mi][ni][reg];
      }
}

extern "C" void kernel_launch(void* const* d_in, const int* in_sizes, int n_in,
                              void* d_out, int out_size, void* d_ws, size_t ws_size,
                              hipStream_t stream) {
  (void)in_sizes; (void)n_in; (void)out_size;
  const float* x    = (const float*)d_in[0];
  const float* iw   = (const float*)d_in[1];
  const float* bvec = (const float*)d_in[2];
  const float* proj = (const float*)d_in[3];
  const float* xr   = (const float*)d_in[4];
  const float* xi   = (const float*)d_in[5];
  float* out = (float*)d_out;

  char* ws = (char*)d_ws;
  size_t off = 0;
  auto take = [&](size_t bytes) {
    char* p = ws + off;
    off = (off + bytes + 255) & ~(size_t)255;
    return p;
  };
  unsigned short* F      = (unsigned short*)take((size_t)NROWS * KDIM * 2);  // 134 MB
  unsigned short* Wp     = (unsigned short*)take((size_t)OUTD * KDIM * 2);   // 2 MB
  unsigned short* projbf = (unsigned short*)take((size_t)NRF * DIMN * 2);    // 128 KB
  float* mg2 = (float*)take((size_t)NRF * 4);
  if (ws_size < off) return;  // workspace too small: bail cleanly (diagnosable)

  const float  scaleC = sqrtf(1.f + 4.f * MCOEF);                 // sqrt(1.004)
  const double c2d    = 0.5 * exp(128.0 * log(1.0 + 4.0 * 0.001));// c^2
  const float  invSR  = 0.0625f;                                   // 1/sqrt(256)
  const float  sRw    = (float)(c2d * 0.0625);

  prep_rf<<<NRF, 64, 0, stream>>>(proj, projbf, mg2);
  fused_features<<<NROWS / 64, 256, 0, stream>>>(
      x, 1.f / DIMN, nullptr, 0.f, xr, xi, mg2, projbf, F, invSR, invSR, scaleC);
  fused_features<<<OUTD / 64, 256, 0, stream>>>(
      iw, 0.25f, bvec, 0.25f, xr, xi, mg2, projbf, Wp, sRw, -sRw, scaleC);
  gemm_bt<<<4096, 256, 0, stream>>>(F, Wp, out);
}